// Round 1
// baseline (166.569 us; speedup 1.0000x reference)
//
#include <hip/hip_runtime.h>
#include <hip/hip_bf16.h>
#include <stdint.h>

#define N_SAMPLES 4096
#define M_ROWS 16
#define K_DIM 256
#define H_DIM 256
#define N_CATS 64
#define SPB 4                                        // samples per group (64 rows)
#define MAX_PADDED (N_SAMPLES + N_CATS * (SPB - 1))  // 4288
#define NGROUP (MAX_PADDED / SPB)                    // 1072
#define GPX (NGROUP / 8)                             // 134 groups per XCD

typedef _Float16 half8 __attribute__((ext_vector_type(8)));
typedef _Float16 half4 __attribute__((ext_vector_type(4)));
typedef float floatx4 __attribute__((ext_vector_type(4)));

// ---- workspace layout ----
#define WT_BYTES ((size_t)N_CATS * K_DIM * H_DIM * 2)  // 8 MB f16 W^T
#define GCAT_OFF WT_BYTES                              // NGROUP ints (4288 B, 16B-mult)
#define ORD_OFF  (WT_BYTES + 4288)
#define WS_NEED  (ORD_OFF + (size_t)MAX_PADDED * 4)

// ---------------- fused prep: transpose (blocks 0..1023) + bucketing (block 1024) ----
__global__ __launch_bounds__(256)
void prep_combined(const float* __restrict__ W, _Float16* __restrict__ Wt,
                   const int* __restrict__ cat, int* __restrict__ ord,
                   int* __restrict__ gcat) {
  const int tid = threadIdx.x;
  if (blockIdx.x < 1024) {
    __shared__ _Float16 t[64][72];
    const int bid = blockIdx.x;
    const int c  = bid >> 4;
    const int kb = (bid >> 2) & 3;
    const int hb = bid & 3;
    const int r  = tid >> 2;
    const int cg = (tid & 3) * 16;
    const float* src = W + ((size_t)c << 16) + (size_t)(kb * 64 + r) * 256 + hb * 64 + cg;
#pragma unroll
    for (int j = 0; j < 16; j += 4) {
      float4 v = *(const float4*)(src + j);
      t[r][cg + j + 0] = (_Float16)v.x;
      t[r][cg + j + 1] = (_Float16)v.y;
      t[r][cg + j + 2] = (_Float16)v.z;
      t[r][cg + j + 3] = (_Float16)v.w;
    }
    __syncthreads();
    _Float16* dst = Wt + ((size_t)c << 16) + (size_t)(hb * 64 + r) * 256 + kb * 64 + cg;
    half8 o0, o1;
#pragma unroll
    for (int j = 0; j < 8; j++) o0[j] = t[cg + j][r];
#pragma unroll
    for (int j = 0; j < 8; j++) o1[j] = t[cg + 8 + j][r];
    *(half8*)(dst) = o0;
    *(half8*)(dst + 8) = o1;
  } else {
    __shared__ int hist[N_CATS];
    __shared__ int poffs[N_CATS];
    __shared__ int curs[N_CATS];
    if (tid < N_CATS) hist[tid] = 0;
    for (int i = tid; i < MAX_PADDED; i += 256) ord[i] = -1;
    for (int i = tid; i < NGROUP; i += 256) gcat[i] = 0;
    __syncthreads();
    for (int i = tid; i < N_SAMPLES; i += 256) atomicAdd(&hist[cat[i]], 1);
    __syncthreads();
    if (tid == 0) {
      int run = 0;
      for (int c = 0; c < N_CATS; c++) {
        poffs[c] = run;
        run += ((hist[c] + SPB - 1) / SPB) * SPB;
      }
    }
    if (tid < N_CATS) curs[tid] = 0;
    __syncthreads();
    if (tid < N_CATS) {
      const int c = tid;
      const int g0 = poffs[c] >> 2;
      const int ng = (hist[c] + SPB - 1) >> 2;
      for (int g = 0; g < ng; g++) gcat[g0 + g] = c;
    }
    for (int i = tid; i < N_SAMPLES; i += 256) {
      int c = cat[i];
      int p = poffs[c] + atomicAdd(&curs[c], 1);
      ord[p] = i;
    }
  }
}

// ---------------- main GEMM ----------------
// block = 512 thr (8 waves) = one group: 64 rows (4 samples) x FULL 256 cols.
// Wave w owns cols w*32..w*32+31 (same per-wave shape as the 4-wave version),
// so x is staged ONCE per group (was twice: one per h-half).
// A: 32 KB swizzled LDS (col ^ ((row&7)<<3) half-units) -> exactly 32 KB, no pad.
//    Writes: one full row per wave per instr (XOR const per row) -> conflict-free.
//    Reads: b128 spreads quad^l15 over 8 16B slots -> balanced 8 lanes / 4-bank group.
// B: rotating 3-slot register prefetch (2-kt lookahead, 24 VGPR) instead of bf[8][2];
//    per-wave footprint ~82 VGPR -> launch_bounds(512,6): 3 blocks/CU = 24 waves/CU.
__global__ __launch_bounds__(512, 6)
void gemm_kernel(const float* __restrict__ x, const float* __restrict__ bias,
                 const _Float16* __restrict__ Wt, const int* __restrict__ ord,
                 const int* __restrict__ gcat, float* __restrict__ out) {
  __shared__ __align__(16) _Float16 sA[64 * 256];  // 32 KB, XOR-swizzled

  const int tid = threadIdx.x;
  const int B = blockIdx.x;
  const int xcd = B & 7;
  const int group = xcd * GPX + (B >> 3);   // consecutive groups (same cat) -> same XCD

  const int cat = gcat[group];              // independent of ord (gcat pre-zeroed)
  const int4 sm = *(const int4*)(ord + group * 4);
  if (sm.x < 0) return;                     // fully-padded tail group (block-uniform)

  const int wid  = tid >> 6;                // 0..7
  const int lane = tid & 63;
  const int l15  = lane & 15;
  const int quad = lane >> 4;

  const _Float16* wbase = Wt + ((size_t)cat << 16);
  const _Float16* bptr0 = wbase + (size_t)(wid * 32 + 0 * 16 + l15) * K_DIM + quad * 8;
  const _Float16* bptr1 = wbase + (size_t)(wid * 32 + 1 * 16 + l15) * K_DIM + quad * 8;

  // ---- B prologue: kt=0,1 issued FIRST (arrive during A staging + barrier) ----
  half8 bf[3][2];
#pragma unroll
  for (int kt = 0; kt < 2; kt++) {
    bf[kt][0] = *(const half8*)(bptr0 + kt * 32);
    bf[kt][1] = *(const half8*)(bptr1 + kt * 32);
  }
  __builtin_amdgcn_sched_barrier(0);  // keep B issued before A staging

  // ---- A staging: per i, wave w writes row i*8+w (one full row, coalesced 1KB) ----
  const float* b0 = (sm.x >= 0) ? x + ((size_t)sm.x << 12) : nullptr;
  const float* b1 = (sm.y >= 0) ? x + ((size_t)sm.y << 12) : nullptr;
  const float* b2 = (sm.z >= 0) ? x + ((size_t)sm.z << 12) : nullptr;
  const float* b3 = (sm.w >= 0) ? x + ((size_t)sm.w << 12) : nullptr;
  const int wcol = (lane * 4) ^ (wid << 3);  // row%8 == wid -> swizzle const per wave
#pragma unroll
  for (int i = 0; i < 8; i++) {
    // sample index (i*8+wid)>>4 == i>>1 for wid<8: compile-time select
    const float* bs = ((i >> 1) == 0) ? b0 : ((i >> 1) == 1) ? b1 : ((i >> 1) == 2) ? b2 : b3;
    const int row = i * 8 + wid;
    _Float16* adst = sA + row * 256 + wcol;
    if (bs) {
      float4 v = *(const float4*)(bs + (size_t)(((i & 1) * 8 + wid) * 256) + lane * 4);
      half4 h;
      h[0] = (_Float16)v.x; h[1] = (_Float16)v.y;
      h[2] = (_Float16)v.z; h[3] = (_Float16)v.w;
      *(half4*)adst = h;
    } else {
      half4 h;
#pragma unroll
      for (int e = 0; e < 4; e++) h[e] = (_Float16)0.0f;
      *(half4*)adst = h;
    }
  }

  floatx4 acc[4][2];
#pragma unroll
  for (int i = 0; i < 4; i++)
#pragma unroll
    for (int j = 0; j < 2; j++)
#pragma unroll
      for (int e = 0; e < 4; e++) acc[i][j][e] = 0.0f;

  __syncthreads();  // the ONLY barrier

  // ---- MFMA loop: rotating 3-slot B prefetch (2-kt lookahead) ----
  const int swz = (l15 & 7) << 3;
#pragma unroll
  for (int kt = 0; kt < 8; kt++) {
    if (kt < 6) {                       // prefetch kt+2 (compile-time slot index)
      const int nx = (kt + 2) % 3;
      bf[nx][0] = *(const half8*)(bptr0 + (kt + 2) * 32);
      bf[nx][1] = *(const half8*)(bptr1 + (kt + 2) * 32);
    }
    const int cur = kt % 3;
    half8 af[4];
#pragma unroll
    for (int mt = 0; mt < 4; mt++)
      af[mt] = *(const half8*)&sA[(mt * 16 + l15) * 256 + ((kt * 32 + quad * 8) ^ swz)];
#pragma unroll
    for (int mt = 0; mt < 4; mt++) {
      acc[mt][0] = __builtin_amdgcn_mfma_f32_16x16x32_f16(af[mt], bf[cur][0], acc[mt][0], 0, 0, 0);
      acc[mt][1] = __builtin_amdgcn_mfma_f32_16x16x32_f16(af[mt], bf[cur][1], acc[mt][1], 0, 0, 0);
    }
  }

  // ---- epilogue: C/D layout col=lane&15, row=quad*4+reg ----
  float bv[2];
#pragma unroll
  for (int nt = 0; nt < 2; nt++)
    bv[nt] = bias[cat * H_DIM + wid * 32 + nt * 16 + l15];
  const int srow[4] = {sm.x, sm.y, sm.z, sm.w};
#pragma unroll
  for (int mt = 0; mt < 4; mt++) {
    const int s = srow[mt];
    if (s < 0) continue;
    float* obase = out + ((size_t)s << 12);
#pragma unroll
    for (int nt = 0; nt < 2; nt++) {
      const int col = wid * 32 + nt * 16 + l15;
#pragma unroll
      for (int rr = 0; rr < 4; rr++) {
        const int row = quad * 4 + rr;
        obase[(size_t)row * H_DIM + col] = acc[mt][nt][rr] + bv[nt];
      }
    }
  }
}

// ---------------- fallback (ws too small): naive fp32 ----------------
__global__ __launch_bounds__(256)
void naive_kernel(const float* __restrict__ x, const int* __restrict__ cat,
                  const float* __restrict__ W, const float* __restrict__ bias,
                  float* __restrict__ out) {
  __shared__ float sx[16 * 256];
  const int n = blockIdx.x;
  const int tid = threadIdx.x;
  const int c = cat[n];
  const float* xs = x + (size_t)n * 16 * 256;
  for (int i = tid; i < 16 * 256; i += 256) sx[i] = xs[i];
  __syncthreads();
  const float* Wc = W + ((size_t)c << 16);
  float accv[16];
  float bv = bias[c * 256 + tid];
#pragma unroll
  for (int m = 0; m < 16; m++) accv[m] = bv;
  for (int k = 0; k < 256; k++) {
    float w = Wc[(size_t)k * 256 + tid];
#pragma unroll
    for (int m = 0; m < 16; m++) accv[m] += sx[m * 256 + k] * w;
  }
#pragma unroll
  for (int m = 0; m < 16; m++) out[((size_t)n * 16 + m) * 256 + tid] = accv[m];
}

// ---------------- launcher ----------------
extern "C" void kernel_launch(void* const* d_in, const int* in_sizes, int n_in,
                              void* d_out, int out_size, void* d_ws, size_t ws_size,
                              hipStream_t stream) {
  const float* x    = (const float*)d_in[0];
  const int*   cat  = (const int*)d_in[1];
  const float* W    = (const float*)d_in[2];
  const float* bias = (const float*)d_in[3];
  float* out = (float*)d_out;

  if (ws_size < WS_NEED) {
    naive_kernel<<<N_SAMPLES, 256, 0, stream>>>(x, cat, W, bias, out);
    return;
  }

  char* ws = (char*)d_ws;
  _Float16* Wt = (_Float16*)ws;
  int* gcat = (int*)(ws + GCAT_OFF);
  int* ord  = (int*)(ws + ORD_OFF);

  prep_combined<<<1025, 256, 0, stream>>>(W, Wt, cat, ord, gcat);
  gemm_kernel<<<NGROUP, 512, 0, stream>>>(x, bias, Wt, ord, gcat, out);
}